// Round 7
// baseline (497.767 us; speedup 1.0000x reference)
//
#include <hip/hip_runtime.h>
#include <cstdint>

// ---------------------------------------------------------------------------
// q[256][262144], s[512][262144] fp32.
// rank by d2 ~ s2[n] - 2*(q.s)[m][n]; per-row top-10 -> threshold -> row mask
// out = q * mask[row]
// K1: split-K GEMM: fp32 DMA'd to LDS via global_load_lds (XOR-swizzled
//     SOURCE + swizzled READ, linear LDS dest), fp32->bf16 hi/lo split in
//     consume, 3-term MFMA (qh*sh+qh*sl+ql*sh). BN=64 -> 24KB/buffer ->
//     48KB dbuf -> 3 blocks/CU (12 waves/CU) for latency hiding.
// K2: reduce partials + per-row top-10; K3: threshold+mask; K4: masked copy
// ---------------------------------------------------------------------------

typedef __attribute__((ext_vector_type(8))) __bf16 bf16x8;
typedef __attribute__((ext_vector_type(4))) float f32x4;
typedef __attribute__((ext_vector_type(4))) unsigned int uintx4;

#define KTOT 262144
#define MQ 256
#define NS 512
#define KSPLIT 128
#define KC 2048                 // KTOT / KSPLIT
#define BK 32
#define NSTEPS 64               // KC / BK
#define BOFF 16384              // B region offset inside buffer (A = 128x32 f32)
#define BUFBYTES 24576          // A 16K + B 8K

__device__ inline void gld16(const float* g, void* l) {
    __builtin_amdgcn_global_load_lds(
        (const __attribute__((address_space(1))) void*)g,
        (__attribute__((address_space(3))) void*)l,
        16, 0, 0);
}

__device__ inline unsigned int cvtpk_bf16(float a, float b) {
    unsigned int r;
    asm("v_cvt_pk_bf16_f32 %0, %1, %2" : "=v"(r) : "v"(a), "v"(b));
    return r; // r[15:0]=bf16(a), r[31:16]=bf16(b)
}

__device__ inline void split2(float a, float b, unsigned int& h, unsigned int& l) {
    h = cvtpk_bf16(a, b);
    float ra = a - __uint_as_float(h << 16);          // exact (Sterbenz)
    float rb = b - __uint_as_float(h & 0xFFFF0000u);  // exact
    l = cvtpk_bf16(ra, rb);
}

// 8 consecutive fp32 (two float4) -> bf16x8 hi + bf16x8 lo
__device__ inline void split8v(const float4& x, const float4& y, bf16x8& hv, bf16x8& lv) {
    unsigned int h0, h1, h2, h3, l0, l1, l2, l3;
    split2(x.x, x.y, h0, l0);
    split2(x.z, x.w, h1, l1);
    split2(y.x, y.y, h2, l2);
    split2(y.z, y.w, h3, l3);
    uintx4 h = (uintx4){h0, h1, h2, h3};
    uintx4 l = (uintx4){l0, l1, l2, l3};
    hv = __builtin_bit_cast(bf16x8, h);
    lv = __builtin_bit_cast(bf16x8, l);
}

// ---------------------------------------------------------------------------
// K1: grid = 2048 = 128 chunks x 2 mtiles x 8 ntiles, XCD-swizzled so a
// chunk's 16 sibling blocks co-run on one XCD (Q k-slice = 2MB -> L2-resident).
// block = 256 threads (4 waves, 2x2 wave grid, wave tile 64x32).
// ---------------------------------------------------------------------------
__global__ __launch_bounds__(256, 3)
void k1_gemm(const float* __restrict__ Q, const float* __restrict__ S,
             float* __restrict__ Ppart, float* __restrict__ s2part)
{
    __shared__ __align__(16) unsigned char Lds[2 * BUFBYTES];   // 48 KiB

    const int tid  = threadIdx.x;
    const int lane = tid & 63;
    const int w    = tid >> 6;            // wave 0..3
    const int wm   = w >> 1;              // 0..1 (64-row band)
    const int wn   = w & 1;               // 0..1 (32-col band)
    const int lr   = lane & 15;
    const int lk   = lane >> 4;

    const int phys = blockIdx.x;
    const int xcd  = phys & 7;
    const int ord  = phys >> 3;           // 0..255
    const int chunk = xcd * 16 + (ord >> 4);
    const int sub  = ord & 15;
    const int mtile = sub >> 3;           // 0..1
    const int ntile = sub & 7;            // 0..7
    const long k0  = (long)chunk * KC;

    // --- staging source pointers: 6 global_load_lds per wave per step.
    // slot s = (i*4+w)*64 + lane covers LDS 16B-slot s (linear dest);
    // source chunk is XOR-swizzled: LDS slot (row,u) <- global chunk u^(row&7).
    const float* gsrc[6];
#pragma unroll
    for (int i = 0; i < 6; ++i) {
        int s = (i * 4 + w) * 64 + lane;       // 0..1535
        const float* base;
        int r, u;
        if (s < 1024) {                         // A: 128 rows x 8 slots
            r = s >> 3; u = s & 7;
            base = Q + (long)(mtile * 128 + r) * KTOT;
        } else {                                // B: 64 rows x 8 slots
            int sb = s - 1024;
            r = sb >> 3; u = sb & 7;
            base = S + (long)(ntile * 64 + r) * KTOT;
        }
        int c = u ^ (r & 7);                    // swizzled source chunk
        gsrc[i] = base + k0 + c * 4;
    }

    // --- LDS read byte-offsets (swizzled to match): row r, float4 chunk c
    // lives at byte r*128 + (c^(r&7))*16 (+BOFF for B).
    int aoffB[4][2], boffB[2][2];
#pragma unroll
    for (int i = 0; i < 4; ++i) {
        int ra = wm * 64 + i * 16 + lr;
#pragma unroll
        for (int t = 0; t < 2; ++t)
            aoffB[i][t] = ra * 128 + (((lk * 2 + t) ^ (lr & 7)) * 16);
    }
#pragma unroll
    for (int j = 0; j < 2; ++j) {
        int rb = wn * 32 + j * 16 + lr;
#pragma unroll
        for (int t = 0; t < 2; ++t)
            boffB[j][t] = BOFF + rb * 128 + (((lk * 2 + t) ^ (lr & 7)) * 16);
    }

    f32x4 acc[4][2];
#pragma unroll
    for (int i = 0; i < 4; ++i)
#pragma unroll
        for (int j = 0; j < 2; ++j)
            acc[i][j] = (f32x4){0.f, 0.f, 0.f, 0.f};
    float ssq[2] = {0.f, 0.f};

#define STAGE(BUFBASE)                                                    \
    {                                                                     \
        _Pragma("unroll")                                                 \
        for (int i = 0; i < 6; ++i) {                                     \
            gld16(gsrc[i], &Lds[(BUFBASE) + (i * 4 + w) * 1024]);         \
            gsrc[i] += BK;                                                \
        }                                                                 \
    }

    STAGE(0)                               // tile 0 -> buf0
    for (int s = 0; s < NSTEPS; ++s) {
        const int cur = (s & 1) * BUFBYTES;
        __syncthreads();                   // drains DMA for cur; frees other buf
        if (s + 1 < NSTEPS) STAGE(((s + 1) & 1) * BUFBYTES)
        // consume: read fp32 frags from LDS, split to bf16 hi/lo, 24 MFMAs
        bf16x8 ah[4], al[4], bh[2], bl[2];
#pragma unroll
        for (int i = 0; i < 4; ++i) {
            float4 x = *(const float4*)&Lds[cur + aoffB[i][0]];
            float4 y = *(const float4*)&Lds[cur + aoffB[i][1]];
            split8v(x, y, ah[i], al[i]);
        }
#pragma unroll
        for (int j = 0; j < 2; ++j) {
            float4 u = *(const float4*)&Lds[cur + boffB[j][0]];
            float4 v = *(const float4*)&Lds[cur + boffB[j][1]];
            split8v(u, v, bh[j], bl[j]);
            ssq[j] += u.x*u.x + u.y*u.y + u.z*u.z + u.w*u.w
                    + v.x*v.x + v.y*v.y + v.z*v.z + v.w*v.w;
        }
#pragma unroll
        for (int i = 0; i < 4; ++i)
#pragma unroll
            for (int j = 0; j < 2; ++j) {
                acc[i][j] = __builtin_amdgcn_mfma_f32_16x16x32_bf16(ah[i], bh[j], acc[i][j], 0, 0, 0);
                acc[i][j] = __builtin_amdgcn_mfma_f32_16x16x32_bf16(ah[i], bl[j], acc[i][j], 0, 0, 0);
                acc[i][j] = __builtin_amdgcn_mfma_f32_16x16x32_bf16(al[i], bh[j], acc[i][j], 0, 0, 0);
            }
    }
#undef STAGE

    // s2 partials: lane ssq[j] covers B row wn*32+j*16+lr, k-quarter lk.
    // wm and mtile duplicate the computation -> gate writes.
#pragma unroll
    for (int j = 0; j < 2; ++j) {
        float v = ssq[j];
        v += __shfl_xor(v, 16);
        v += __shfl_xor(v, 32);
        if (lk == 0 && wm == 0 && mtile == 0)
            s2part[chunk * NS + ntile * 64 + wn * 32 + j * 16 + lr] = v;
    }

    // write q.s partial tile  (C/D layout: col=lane&15, row=(lane>>4)*4+reg)
    float* op = Ppart + (long)chunk * (MQ * NS);
#pragma unroll
    for (int i = 0; i < 4; ++i)
#pragma unroll
        for (int j = 0; j < 2; ++j) {
            int mb = mtile * 128 + wm * 64 + i * 16 + lk * 4;
            int nn = ntile * 64 + wn * 32 + j * 16 + lr;
#pragma unroll
            for (int r = 0; r < 4; ++r)
                op[(long)(mb + r) * NS + nn] = acc[i][j][r];
        }
}

// ---------------------------------------------------------------------------
// K2: one block per query row: reduce K-split partials -> d2 row -> top-10
// ---------------------------------------------------------------------------
__global__ __launch_bounds__(256)
void k2_topk(const float* __restrict__ Ppart, const float* __restrict__ s2part,
             int* __restrict__ idxb)
{
    __shared__ float d2s[NS];
    const int m = blockIdx.x;
    const int tid = threadIdx.x;
    for (int nn = tid; nn < NS; nn += 256) {
        float s2 = 0.f, p = 0.f;
        for (int c = 0; c < KSPLIT; ++c) {
            s2 += s2part[c * NS + nn];
            p  += Ppart[(long)c * (MQ * NS) + (long)m * NS + nn];
        }
        d2s[nn] = s2 - 2.f * p;
    }
    __syncthreads();
    if (tid < 64) {
        unsigned long long key[8];
#pragma unroll
        for (int j = 0; j < 8; ++j) {
            int n = tid * 8 + j;
            unsigned int u = __float_as_uint(d2s[n]);
            u = (u >> 31) ? ~u : (u | 0x80000000u);   // total order, ascending
            key[j] = ((unsigned long long)u << 32) | (unsigned int)n;
        }
        for (int it = 0; it < 10; ++it) {
            unsigned long long best = key[0];
#pragma unroll
            for (int j = 1; j < 8; ++j) best = key[j] < best ? key[j] : best;
            for (int d = 1; d < 64; d <<= 1) {
                unsigned long long o = __shfl_xor(best, d);
                best = o < best ? o : best;
            }
            if (tid == 0) idxb[m * 10 + it] = (int)(best & 0xFFFFFFFFu);
#pragma unroll
            for (int j = 0; j < 8; ++j) if (key[j] == best) key[j] = ~0ull;
        }
    }
}

// ---------------------------------------------------------------------------
// K3: losses / best_k / threshold / mask  (integer sums < 2^24 -> exact fp32)
// ---------------------------------------------------------------------------
__global__ __launch_bounds__(256)
void k3_thresh(const int* __restrict__ idxb, float* __restrict__ mask)
{
    __shared__ int colsum[10];
    __shared__ float thr;
    const int tid = threadIdx.x;
    if (tid < 10) {
        int s = 0;
        for (int m = 0; m < MQ; ++m) s += idxb[m * 10 + tid];
        colsum[tid] = s;
    }
    __syncthreads();
    if (tid == 0) {
        float pre = 0.f, best = 3.4e38f;
        for (int k = 1; k <= 10; ++k) {
            pre += (float)colsum[k - 1];
            float loss = pre / (256.0f * (float)k);
            if (loss < best) best = loss;   // first-min == argmin; threshold = losses[best_k]
        }
        thr = best;
    }
    __syncthreads();
    if (tid < MQ) mask[tid] = ((float)idxb[tid * 10] < thr) ? 1.0f : 0.0f;
}

// ---------------------------------------------------------------------------
// K4: out = q * mask[row]   (float4, 2^18 floats per row)
// ---------------------------------------------------------------------------
__global__ __launch_bounds__(256)
void k4_apply(const float* __restrict__ Q, const float* __restrict__ mask,
              float* __restrict__ out)
{
    long i = ((long)blockIdx.x * 256 + threadIdx.x) * 4;
    int row = (int)(i >> 18);
    float4 v = *(const float4*)(Q + i);
    float mm = mask[row];
    v.x *= mm; v.y *= mm; v.z *= mm; v.w *= mm;
    *(float4*)(out + i) = v;
}

extern "C" void kernel_launch(void* const* d_in, const int* in_sizes, int n_in,
                              void* d_out, int out_size, void* d_ws, size_t ws_size,
                              hipStream_t stream)
{
    const float* Q = (const float*)d_in[0];
    const float* S = (const float*)d_in[1];
    float* out = (float*)d_out;

    // scratch inside d_out (overwritten by k4 afterwards); only mask must
    // survive into k4, so it lives in d_ws.
    float* Ppart  = out;                                   // 128*256*512 f32 = 64 MiB
    float* s2part = out + (long)KSPLIT * MQ * NS;          // 128*512 f32
    int*   idxb   = (int*)(s2part + KSPLIT * NS);          // 256*10 int
    float* mask   = (float*)d_ws;                          // 256 f32

    hipLaunchKernelGGL(k1_gemm,  dim3(2048),  dim3(256), 0, stream, Q, S, Ppart, s2part);
    hipLaunchKernelGGL(k2_topk,  dim3(MQ),    dim3(256), 0, stream, Ppart, s2part, idxb);
    hipLaunchKernelGGL(k3_thresh,dim3(1),     dim3(256), 0, stream, idxb, mask);
    hipLaunchKernelGGL(k4_apply, dim3(65536), dim3(256), 0, stream, Q, mask, out);
}

// Round 8
// 414.582 us; speedup vs baseline: 1.2006x; 1.2006x over previous
//
#include <hip/hip_runtime.h>
#include <cstdint>

// ---------------------------------------------------------------------------
// q[256][262144], s[512][262144] fp32.
// rank by d2 ~ s2[n] - 2*(q.s)[m][n]; per-row top-10 -> threshold -> row mask
// out = q * mask[row]
// K1: split-K GEMM, R6 geometry (BM=BN=128, 2 blocks/CU) + T3/T4 minimum
//     2-phase counted-vmcnt schedule: STAGE(s+1) issued BEFORE consume(s),
//     s_waitcnt vmcnt(6) (never 0 mid-loop), raw s_barrier + sched_barrier
//     fences. fp32 DMA'd to LDS (XOR-swizzled source + swizzled read, linear
//     dest); fp32->bf16 hi/lo split in consume; 3-term MFMA.
// K2: reduce partials + per-row top-10; K3: threshold+mask; K4: masked copy
// ---------------------------------------------------------------------------

typedef __attribute__((ext_vector_type(8))) __bf16 bf16x8;
typedef __attribute__((ext_vector_type(4))) float f32x4;
typedef __attribute__((ext_vector_type(4))) unsigned int uintx4;

#define KTOT 262144
#define MQ 256
#define NS 512
#define KSPLIT 64
#define KC (KTOT / KSPLIT)      // 4096
#define BK 32
#define NSTEPS (KC / BK)        // 128
#define BUFBYTES 32768          // A 16K + B 16K per buffer
#define BOFF 16384              // B offset inside buffer

__device__ inline void gld16(const float* g, void* l) {
    __builtin_amdgcn_global_load_lds(
        (const __attribute__((address_space(1))) void*)g,
        (__attribute__((address_space(3))) void*)l,
        16, 0, 0);
}

__device__ inline unsigned int cvtpk_bf16(float a, float b) {
    unsigned int r;
    asm("v_cvt_pk_bf16_f32 %0, %1, %2" : "=v"(r) : "v"(a), "v"(b));
    return r; // r[15:0]=bf16(a), r[31:16]=bf16(b)
}

__device__ inline void split2(float a, float b, unsigned int& h, unsigned int& l) {
    h = cvtpk_bf16(a, b);
    float ra = a - __uint_as_float(h << 16);          // exact (Sterbenz)
    float rb = b - __uint_as_float(h & 0xFFFF0000u);  // exact
    l = cvtpk_bf16(ra, rb);
}

// 8 consecutive fp32 (two float4) -> bf16x8 hi + bf16x8 lo
__device__ inline void split8v(const float4& x, const float4& y, bf16x8& hv, bf16x8& lv) {
    unsigned int h0, h1, h2, h3, l0, l1, l2, l3;
    split2(x.x, x.y, h0, l0);
    split2(x.z, x.w, h1, l1);
    split2(y.x, y.y, h2, l2);
    split2(y.z, y.w, h3, l3);
    uintx4 h = (uintx4){h0, h1, h2, h3};
    uintx4 l = (uintx4){l0, l1, l2, l3};
    hv = __builtin_bit_cast(bf16x8, h);
    lv = __builtin_bit_cast(bf16x8, l);
}

// ---------------------------------------------------------------------------
// K1: grid = 512 = 64 chunks x 2 mtiles x 4 ntiles, XCD-swizzled so a chunk's
// 8 sibling blocks co-run on one XCD (L2 reuse of the k-slice).
// block = 256 threads (4 waves, 2x2 wave grid, wave tile 64x64).
// ---------------------------------------------------------------------------
__global__ __launch_bounds__(256, 2)
void k1_gemm(const float* __restrict__ Q, const float* __restrict__ S,
             float* __restrict__ Ppart, float* __restrict__ s2part)
{
    __shared__ __align__(16) unsigned char Lds[2 * BUFBYTES];   // 64 KiB

    const int tid  = threadIdx.x;
    const int lane = tid & 63;
    const int w    = tid >> 6;            // wave 0..3
    const int wm   = w >> 1;
    const int wn   = w & 1;
    const int lr   = lane & 15;
    const int lk   = lane >> 4;

    const int phys = blockIdx.x;
    const int xcd  = phys & 7;
    const int ord  = phys >> 3;           // 0..63
    const int chunk = xcd * 8 + (ord >> 3);
    const int sub  = ord & 7;
    const int mtile = sub >> 2;           // 0..1
    const int ntile = sub & 3;            // 0..3
    const long k0  = (long)chunk * KC;

    // --- staging source pointers: 8 global_load_lds per wave per step.
    // slot s = (i*4+w)*64 + lane covers LDS 16B-slot s (linear dest);
    // source chunk is XOR-swizzled: LDS slot (row,u) <- global chunk u^(row&7).
    const float* gsrc[8];
#pragma unroll
    for (int i = 0; i < 8; ++i) {
        int s    = (i * 4 + w) * 64 + lane;    // 0..2047
        int tile = s >> 10;                    // 0 = A, 1 = B
        int r    = (s & 1023) >> 3;            // row 0..127
        int u    = s & 7;                      // 16B slot within row
        int c    = u ^ (r & 7);                // swizzled source chunk
        const float* base = tile ? (S + (long)(ntile * 128 + r) * KTOT)
                                 : (Q + (long)(mtile * 128 + r) * KTOT);
        gsrc[i] = base + k0 + c * 4;
    }

    // --- LDS read byte-offsets (swizzled to match): row r, float4 chunk c
    // lives at byte r*128 + (c^(r&7))*16 (+BOFF for B).
    int aoffB[4][2], boffB[4][2];
#pragma unroll
    for (int f = 0; f < 4; ++f) {
        int ra = wm * 64 + f * 16 + lr;
        int rb = wn * 64 + f * 16 + lr;
        int sw = lr & 7;
#pragma unroll
        for (int t = 0; t < 2; ++t) {
            aoffB[f][t] = ra * 128 + ((lk * 2 + t) ^ sw) * 16;
            boffB[f][t] = BOFF + rb * 128 + ((lk * 2 + t) ^ sw) * 16;
        }
    }

    f32x4 acc[4][4];
#pragma unroll
    for (int i = 0; i < 4; ++i)
#pragma unroll
        for (int j = 0; j < 4; ++j)
            acc[i][j] = (f32x4){0.f, 0.f, 0.f, 0.f};
    float ssq[4] = {0.f, 0.f, 0.f, 0.f};

#define STAGE(BUFBASE)                                                    \
    {                                                                     \
        _Pragma("unroll")                                                 \
        for (int i = 0; i < 8; ++i) {                                     \
            gld16(gsrc[i], &Lds[(BUFBASE) + (i * 4 + w) * 1024]);         \
            gsrc[i] += BK;                                                \
        }                                                                 \
    }

    STAGE(0)                               // tile 0 -> buf0
    for (int s = 0; s < NSTEPS; ++s) {
        const int cur = (s & 1) * BUFBYTES;
        // T3/T4: issue next tile's DMA FIRST; counted vmcnt keeps its 6 loads
        // in flight across both barriers; only tile s's loads are awaited.
        if (s + 1 < NSTEPS) {
            STAGE(((s + 1) & 1) * BUFBYTES)
            asm volatile("s_waitcnt vmcnt(6)" ::: "memory");
        } else {
            asm volatile("s_waitcnt vmcnt(0)" ::: "memory");
        }
        __builtin_amdgcn_sched_barrier(0);
        __builtin_amdgcn_s_barrier();      // all waves: buf[cur] fully written
        __builtin_amdgcn_sched_barrier(0);

        // consume: read fp32 frags from LDS, split to bf16 hi/lo, 48 MFMAs
        bf16x8 ah[4], al[4], bh[4], bl[4];
#pragma unroll
        for (int f = 0; f < 4; ++f) {
            float4 x = *(const float4*)&Lds[cur + aoffB[f][0]];
            float4 y = *(const float4*)&Lds[cur + aoffB[f][1]];
            split8v(x, y, ah[f], al[f]);
            float4 u = *(const float4*)&Lds[cur + boffB[f][0]];
            float4 v = *(const float4*)&Lds[cur + boffB[f][1]];
            split8v(u, v, bh[f], bl[f]);
            ssq[f] += u.x*u.x + u.y*u.y + u.z*u.z + u.w*u.w
                    + v.x*v.x + v.y*v.y + v.z*v.z + v.w*v.w;
        }
#pragma unroll
        for (int i = 0; i < 4; ++i)
#pragma unroll
            for (int j = 0; j < 4; ++j) {
                acc[i][j] = __builtin_amdgcn_mfma_f32_16x16x32_bf16(ah[i], bh[j], acc[i][j], 0, 0, 0);
                acc[i][j] = __builtin_amdgcn_mfma_f32_16x16x32_bf16(ah[i], bl[j], acc[i][j], 0, 0, 0);
                acc[i][j] = __builtin_amdgcn_mfma_f32_16x16x32_bf16(al[i], bh[j], acc[i][j], 0, 0, 0);
            }

        // end-of-step barrier: no wave may overwrite buf[cur] (next STAGE)
        // until every wave's reads of it completed (lgkm drained before MFMA).
        __builtin_amdgcn_sched_barrier(0);
        __builtin_amdgcn_s_barrier();
        __builtin_amdgcn_sched_barrier(0);
    }
#undef STAGE

    // s2 partials: lane ssq[f] covers B row wn*64+f*16+lr, k-quarter lk.
    // wm and mtile duplicate the computation -> gate writes.
#pragma unroll
    for (int f = 0; f < 4; ++f) {
        float v = ssq[f];
        v += __shfl_xor(v, 16);
        v += __shfl_xor(v, 32);
        if (lk == 0 && wm == 0 && mtile == 0)
            s2part[chunk * NS + ntile * 128 + wn * 64 + f * 16 + lr] = v;
    }

    // write q.s partial tile  (C/D layout: col=lane&15, row=(lane>>4)*4+reg)
    float* op = Ppart + (long)chunk * (MQ * NS);
#pragma unroll
    for (int i = 0; i < 4; ++i)
#pragma unroll
        for (int j = 0; j < 4; ++j) {
            int mb = mtile * 128 + wm * 64 + i * 16 + lk * 4;
            int nn = ntile * 128 + wn * 64 + j * 16 + lr;
#pragma unroll
            for (int r = 0; r < 4; ++r)
                op[(long)(mb + r) * NS + nn] = acc[i][j][r];
        }
}

// ---------------------------------------------------------------------------
// K2: one block per query row: reduce K-split partials -> d2 row -> top-10
// ---------------------------------------------------------------------------
__global__ __launch_bounds__(256)
void k2_topk(const float* __restrict__ Ppart, const float* __restrict__ s2part,
             int* __restrict__ idxb)
{
    __shared__ float d2s[NS];
    const int m = blockIdx.x;
    const int tid = threadIdx.x;
    for (int nn = tid; nn < NS; nn += 256) {
        float s2 = 0.f, p = 0.f;
        for (int c = 0; c < KSPLIT; ++c) {
            s2 += s2part[c * NS + nn];
            p  += Ppart[(long)c * (MQ * NS) + (long)m * NS + nn];
        }
        d2s[nn] = s2 - 2.f * p;
    }
    __syncthreads();
    if (tid < 64) {
        unsigned long long key[8];
#pragma unroll
        for (int j = 0; j < 8; ++j) {
            int n = tid * 8 + j;
            unsigned int u = __float_as_uint(d2s[n]);
            u = (u >> 31) ? ~u : (u | 0x80000000u);   // total order, ascending
            key[j] = ((unsigned long long)u << 32) | (unsigned int)n;
        }
        for (int it = 0; it < 10; ++it) {
            unsigned long long best = key[0];
#pragma unroll
            for (int j = 1; j < 8; ++j) best = key[j] < best ? key[j] : best;
            for (int d = 1; d < 64; d <<= 1) {
                unsigned long long o = __shfl_xor(best, d);
                best = o < best ? o : best;
            }
            if (tid == 0) idxb[m * 10 + it] = (int)(best & 0xFFFFFFFFu);
#pragma unroll
            for (int j = 0; j < 8; ++j) if (key[j] == best) key[j] = ~0ull;
        }
    }
}

// ---------------------------------------------------------------------------
// K3: losses / best_k / threshold / mask  (integer sums < 2^24 -> exact fp32)
// ---------------------------------------------------------------------------
__global__ __launch_bounds__(256)
void k3_thresh(const int* __restrict__ idxb, float* __restrict__ mask)
{
    __shared__ int colsum[10];
    __shared__ float thr;
    const int tid = threadIdx.x;
    if (tid < 10) {
        int s = 0;
        for (int m = 0; m < MQ; ++m) s += idxb[m * 10 + tid];
        colsum[tid] = s;
    }
    __syncthreads();
    if (tid == 0) {
        float pre = 0.f, best = 3.4e38f;
        for (int k = 1; k <= 10; ++k) {
            pre += (float)colsum[k - 1];
            float loss = pre / (256.0f * (float)k);
            if (loss < best) best = loss;   // first-min == argmin; threshold = losses[best_k]
        }
        thr = best;
    }
    __syncthreads();
    if (tid < MQ) mask[tid] = ((float)idxb[tid * 10] < thr) ? 1.0f : 0.0f;
}

// ---------------------------------------------------------------------------
// K4: out = q * mask[row]   (float4, 2^18 floats per row)
// ---------------------------------------------------------------------------
__global__ __launch_bounds__(256)
void k4_apply(const float* __restrict__ Q, const float* __restrict__ mask,
              float* __restrict__ out)
{
    long i = ((long)blockIdx.x * 256 + threadIdx.x) * 4;
    int row = (int)(i >> 18);
    float4 v = *(const float4*)(Q + i);
    float mm = mask[row];
    v.x *= mm; v.y *= mm; v.z *= mm; v.w *= mm;
    *(float4*)(out + i) = v;
}

extern "C" void kernel_launch(void* const* d_in, const int* in_sizes, int n_in,
                              void* d_out, int out_size, void* d_ws, size_t ws_size,
                              hipStream_t stream)
{
    const float* Q = (const float*)d_in[0];
    const float* S = (const float*)d_in[1];
    float* out = (float*)d_out;

    // scratch inside d_out (overwritten by k4 afterwards); only mask must
    // survive into k4, so it lives in d_ws.
    float* Ppart  = out;                                   // 64*256*512 f32 = 32 MiB
    float* s2part = out + (long)KSPLIT * MQ * NS;          // 64*512 f32
    int*   idxb   = (int*)(s2part + KSPLIT * NS);          // 256*10 int
    float* mask   = (float*)d_ws;                          // 256 f32

    hipLaunchKernelGGL(k1_gemm,  dim3(512),   dim3(256), 0, stream, Q, S, Ppart, s2part);
    hipLaunchKernelGGL(k2_topk,  dim3(MQ),    dim3(256), 0, stream, Ppart, s2part, idxb);
    hipLaunchKernelGGL(k3_thresh,dim3(1),     dim3(256), 0, stream, idxb, mask);
    hipLaunchKernelGGL(k4_apply, dim3(65536), dim3(256), 0, stream, Q, mask, out);
}